// Round 13
// baseline (388.893 us; speedup 1.0000x reference)
//
#include <hip/hip_runtime.h>
#include <hip/hip_bf16.h>

#define B 32
#define C_IN 192
#define T 8192
#define H 192
#define N_PH 1024
#define OUT 4
#define ROWP (2 * H)          // specT row pitch: hi plane [0,H), lo plane [H,2H)
#define HPITCH 392            // hbuf row pitch (ushort): 784B, 16B-aligned
#define TILE 32               // output rows per chain block

typedef __attribute__((ext_vector_type(8))) short short8;
typedef __attribute__((ext_vector_type(4))) float f32x4;
typedef unsigned short ushort_t;

__device__ inline ushort_t f2bf(float f) {
    unsigned u = __builtin_bit_cast(unsigned, f);
    unsigned r = u + 0x7fffu + ((u >> 16) & 1u);   // RNE
    return (ushort_t)(r >> 16);
}
__device__ inline float bf2f(ushort_t h) {
    unsigned u = ((unsigned)h) << 16;
    return __builtin_bit_cast(float, u);
}
// split x into hi+lo bf16 pair (~17-bit effective mantissa) -- accuracy-mandatory
__device__ inline void split_bf(float x, ushort_t& hi, ushort_t& lo) {
    hi = f2bf(x);
    lo = f2bf(x - bf2f(hi));
}

// ---------------- weight prep: MFMA-fragment-ordered, split hi/lo -----------
__device__ inline void wfrag_one(const float* __restrict__ w, ushort_t* __restrict__ wtf,
                                 int taps, int idx, int ntot) {
    int j  = idx & 7;
    int l  = (idx >> 3) & 63;
    int slot = idx >> 9;             // (kt*6 + s)*12 + nt
    int nt = slot % 12;
    int ss = (slot / 12) % 6;
    int kt = slot / 72;
    int o  = nt * 16 + (l & 15);
    int i  = ss * 32 + ((l >> 4) << 3) + j;
    float v = (taps == 1) ? w[o * C_IN + i] : w[(o * H + i) * 3 + kt];
    ushort_t hi, lo;
    split_bf(v, hi, lo);
    wtf[idx] = hi;
    wtf[idx + ntot] = lo;
}

#define NWF 1008   // ceil((36864 + 2*110592)/256)
__global__ __launch_bounds__(256) void prep_kernel(
    const float* __restrict__ pw, const float* __restrict__ w0,
    const float* __restrict__ w1, const int* __restrict__ wdur,
    ushort_t* __restrict__ wpre, ushort_t* __restrict__ w0t,
    ushort_t* __restrict__ w1t, int* __restrict__ ends)
{
    int blk = blockIdx.x;
    int tid = threadIdx.x;
    const int n1 = 36864, n3 = 110592;
    if (blk < NWF) {
        int idx = blk * 256 + tid;
        if (idx < n1) { wfrag_one(pw, wpre, 1, idx, n1); return; }
        idx -= n1;
        if (idx < n3) { wfrag_one(w0, w0t, 3, idx, n3); return; }
        idx -= n3;
        if (idx < n3) wfrag_one(w1, w1t, 3, idx, n3);
        return;
    }
    int b = blk - NWF;
    __shared__ int part[256];
    int4 w4 = ((const int4*)(wdur + b * N_PH))[tid];
    int c0 = w4.x, c1 = c0 + w4.y, c2 = c1 + w4.z, c3 = c2 + w4.w;
    part[tid] = c3;
    __syncthreads();
    for (int off = 1; off < 256; off <<= 1) {
        int v = (tid >= off) ? part[tid - off] : 0;
        __syncthreads();
        part[tid] += v;
        __syncthreads();
    }
    int pre = tid ? part[tid - 1] : 0;
    int4 e4;
    e4.x = pre + c0; e4.y = pre + c1; e4.z = pre + c2; e4.w = pre + c3;
    ((int4*)(ends + b * N_PH))[tid] = e4;
}

// ---------------- segment mean, direct to time-major split-bf16 specT ----------------
__global__ __launch_bounds__(256) void segmean_direct_kernel(
    const float* __restrict__ x, const int* __restrict__ ends,
    ushort_t* __restrict__ specT)
{
    int b  = blockIdx.x >> 5;
    int jt = (blockIdx.x & 31) * 32;
    int tid = threadIdx.x;
    int j_loc = tid & 31;
    int cg0 = tid >> 5;            // 0..7
    int j = jt + j_loc;

    __shared__ float sm[32][193];

    const int* eb = ends + b * N_PH;
    int e0 = eb[j];
    int s0 = j ? eb[j - 1] : 0;
    int len = e0 - s0;
    float inv = (len > 0) ? 1.f / (float)len : 0.f;

    const float* xb = x + (size_t)b * C_IN * T;
#pragma unroll 1
    for (int c = cg0; c < C_IN; c += 8) {
        const float* xr = xb + (size_t)c * T;
        float sum = 0.f;
        for (int t = s0; t < e0; ++t) sum += xr[t];
        sm[j_loc][c] = sum * inv;
    }
    __syncthreads();

    int r = tid >> 3;
    int g = tid & 7;
    ushort_t* ob = specT + ((size_t)b * N_PH + jt + r) * ROWP;
#pragma unroll
    for (int i0 = 0; i0 < 24; i0 += 8) {
        ushort_t th[8], tl[8];
#pragma unroll
        for (int k2 = 0; k2 < 8; ++k2) {
            int c = g * 24 + i0 + k2;
            split_bf(sm[r][c], th[k2], tl[k2]);
        }
        *(short8*)(ob + g * 24 + i0) = *(short8*)th;
        *(short8*)(ob + H + g * 24 + i0) = *(short8*)tl;
    }
}

// ---------------- fused chain, TILE=32, register double-buffered prefetch ----
// One block = 32 output rows. hbuf rows (local l):
//   h0: l=0..35  <-> pre-linear rows t0-2+l   (P: frags base 0,16 | mgrp1 base 32, keep l<36)
//   h1: l=0..33  <-> conv0 rows    t0-1+l     (C0: frags base 0,16 | mgrp1 base 18, keep l>=32)
//   w : l=0..31  <-> conv1 rows    t0+l       (C1: frag base mgrp*16)
// m_s[i] = mask at t0-2+i (0 outside [0,N_PH)) implements conv zero-padding.
// R12 evidence: occupancy 2->4 blocks/CU gained ~10us only -> the stall is
// within-wave load->wait->MFMA serialization. This version restores the R1
// p/q prefetch (load it+1 while computing it) in all three MFMA stages.
// VGPR grows (~190); occupancy 2 blocks/CU is the intentional trade.

#define P_LOAD(S, AH, AL, BH, BL) do {                                              \
    _Pragma("unroll") for (int f_ = 0; f_ < 2; ++f_) {                              \
        if (f_ < nf) {                                                              \
            int fb_ = mgrp ? 32 : f_ * 16;                                          \
            int trow_ = t0 - 2 + fb_ + m;                                           \
            if ((unsigned)trow_ < (unsigned)N_PH) {                                 \
                const ushort_t* ar_ = inb + (size_t)trow_ * ROWP + (S) * 32 + kg;   \
                AH[f_] = *(const short8*)ar_;                                       \
                AL[f_] = *(const short8*)(ar_ + H);                                 \
            } else { AH[f_] = z8; AL[f_] = z8; }                                    \
        }                                                                           \
    }                                                                               \
    const ushort_t* wb_ = wpre + ((size_t)((S) * 12 + nhalf * 6) << 9) + (lane << 3); \
    _Pragma("unroll") for (int n_ = 0; n_ < 6; ++n_) {                              \
        BH[n_] = *(const short8*)(wb_ + (n_ << 9));                                 \
        BL[n_] = *(const short8*)(wb_ + (n_ << 9) + 36864); }                       \
} while (0)

#define FRAG_MFMA2(AH, AL, BH, BL) do {                                             \
    _Pragma("unroll") for (int f_ = 0; f_ < 2; ++f_) {                              \
        if (f_ < nf) {                                                              \
            _Pragma("unroll") for (int n_ = 0; n_ < 6; ++n_) {                      \
                acc[f_][n_] = __builtin_amdgcn_mfma_f32_16x16x32_bf16(AH[f_], BH[n_], acc[f_][n_], 0, 0, 0); \
                acc[f_][n_] = __builtin_amdgcn_mfma_f32_16x16x32_bf16(AL[f_], BH[n_], acc[f_][n_], 0, 0, 0); \
                acc[f_][n_] = __builtin_amdgcn_mfma_f32_16x16x32_bf16(AH[f_], BL[n_], acc[f_][n_], 0, 0, 0); \
            }                                                                       \
        }                                                                           \
    }                                                                               \
} while (0)

#define C0_LOAD(IT, AH, AL, BH, BL) do {                                            \
    int kt_ = (IT) / 6, s_ = (IT) - kt_ * 6;                                        \
    _Pragma("unroll") for (int f_ = 0; f_ < 2; ++f_) {                              \
        if (f_ < nf) {                                                              \
            int fb_ = mgrp ? 18 : f_ * 16;                                          \
            const ushort_t* ar_ = hbuf + (fb_ + m + kt_) * HPITCH + s_ * 32 + kg;   \
            AH[f_] = *(const short8*)ar_;                                           \
            AL[f_] = *(const short8*)(ar_ + H);                                     \
        }                                                                           \
    }                                                                               \
    const ushort_t* wb_ = w0t + ((size_t)((kt_ * 6 + s_) * 12 + nhalf * 6) << 9) + (lane << 3); \
    _Pragma("unroll") for (int n_ = 0; n_ < 6; ++n_) {                              \
        BH[n_] = *(const short8*)(wb_ + (n_ << 9));                                 \
        BL[n_] = *(const short8*)(wb_ + (n_ << 9) + 110592); }                      \
} while (0)

#define C1_LOAD(IT, AH, AL, BH, BL) do {                                            \
    int kt_ = (IT) / 6, s_ = (IT) - kt_ * 6;                                        \
    const ushort_t* ar_ = hbuf + (mgrp * 16 + m + kt_) * HPITCH + s_ * 32 + kg;     \
    AH = *(const short8*)ar_;                                                       \
    AL = *(const short8*)(ar_ + H);                                                 \
    const ushort_t* wb_ = w1t + ((size_t)((kt_ * 6 + s_) * 12 + nhalf * 6) << 9) + (lane << 3); \
    _Pragma("unroll") for (int n_ = 0; n_ < 6; ++n_) {                              \
        BH[n_] = *(const short8*)(wb_ + (n_ << 9));                                 \
        BL[n_] = *(const short8*)(wb_ + (n_ << 9) + 110592); }                      \
} while (0)

#define C1_MFMA(AH, AL, BH, BL) do {                                                \
    _Pragma("unroll") for (int n_ = 0; n_ < 6; ++n_) {                              \
        acc1[n_] = __builtin_amdgcn_mfma_f32_16x16x32_bf16(AH, BH[n_], acc1[n_], 0, 0, 0); \
        acc1[n_] = __builtin_amdgcn_mfma_f32_16x16x32_bf16(AL, BH[n_], acc1[n_], 0, 0, 0); \
        acc1[n_] = __builtin_amdgcn_mfma_f32_16x16x32_bf16(AH, BL[n_], acc1[n_], 0, 0, 0); \
    }                                                                               \
} while (0)

__global__ __launch_bounds__(256) void chain_kernel(
    const ushort_t* __restrict__ specT,
    const ushort_t* __restrict__ wpre, const ushort_t* __restrict__ w0t,
    const ushort_t* __restrict__ w1t,
    const float* __restrict__ pre_b, const float* __restrict__ c0_b,
    const float* __restrict__ c1_b,
    const float* __restrict__ mask,
    const float* __restrict__ g0, const float* __restrict__ be0,
    const float* __restrict__ g1, const float* __restrict__ be1,
    const float* __restrict__ lw, const float* __restrict__ lb,
    float* __restrict__ out)
{
    const int b  = blockIdx.y;
    const int t0 = blockIdx.x * TILE;
    const int tid = threadIdx.x;
    const int lane = tid & 63;
    const int wv = tid >> 6;
    const int nhalf = wv >> 1;          // output-channel half: cols nhalf*96..+95
    const int mgrp = wv & 1;            // M-frag group
    const int m = lane & 15;
    const int kg = (lane >> 4) << 3;
    const int rbase = (lane >> 4) << 2;

    __shared__ ushort_t hbuf[36 * HPITCH];          // 28.2 KB
    __shared__ float g0_s[H], b0_s[H], g1_s[H], b1_s[H];
    __shared__ float lw_s[OUT * H];
    __shared__ float m_s[36], mstat[34], rstat[34];

    if (tid < H) { g0_s[tid] = g0[tid]; b0_s[tid] = be0[tid];
                   g1_s[tid] = g1[tid]; b1_s[tid] = be1[tid]; }
    if (tid < 36) {
        int grow = t0 - 2 + tid;
        m_s[tid] = (grow >= 0 && grow < N_PH) ? mask[b * N_PH + grow] : 0.f;
    }
    for (int i = tid; i < OUT * H; i += 256) lw_s[i] = lw[i];
    __syncthreads();

    const short8 z8 = {0, 0, 0, 0, 0, 0, 0, 0};

    // double-buffer operand registers shared across stages
    short8 pah[2], pal[2], pbh[6], pbl[6];
    short8 qah[2], qal[2], qbh[6], qbl[6];

    // ================= stage P: pre-linear (taps=1, K=192), prefetched ======
    {
        const int nf = mgrp ? 1 : 2;
        f32x4 acc[2][6];
#pragma unroll
        for (int n = 0; n < 6; ++n) {
            float bb = pre_b[(nhalf * 6 + n) * 16 + m];
            acc[0][n] = (f32x4){bb, bb, bb, bb};
            acc[1][n] = (f32x4){bb, bb, bb, bb};
        }
        const ushort_t* inb = specT + (size_t)b * N_PH * ROWP;
        P_LOAD(0, pah, pal, pbh, pbl);
#pragma unroll 1
        for (int s = 0; s < 6; s += 2) {
            P_LOAD(s + 1, qah, qal, qbh, qbl);
            FRAG_MFMA2(pah, pal, pbh, pbl);
            if (s + 2 < 6) P_LOAD(s + 2, pah, pal, pbh, pbl);
            FRAG_MFMA2(qah, qal, qbh, qbl);
        }
        // store h0 = pre_out * mask, rows l < 36
#pragma unroll
        for (int f = 0; f < 2; ++f) {
            if (f < nf) {
                int fb = mgrp ? 32 : f * 16;
#pragma unroll
                for (int n = 0; n < 6; ++n) {
                    int col = (nhalf * 6 + n) * 16 + m;
#pragma unroll
                    for (int r = 0; r < 4; ++r) {
                        int l = fb + rbase + r;
                        if (l < 36) {
                            float v = acc[f][n][r] * m_s[l];
                            ushort_t hi, lo; split_bf(v, hi, lo);
                            hbuf[l * HPITCH + col] = hi;
                            hbuf[l * HPITCH + H + col] = lo;
                        }
                    }
                }
            }
        }
    }
    __syncthreads();

    // ================= stage C0: conv0 (taps=3), prefetched ======
    {
        const int nf = mgrp ? 1 : 2;
        f32x4 acc[2][6];
#pragma unroll
        for (int n = 0; n < 6; ++n) {
            float bb = c0_b[(nhalf * 6 + n) * 16 + m];
            acc[0][n] = (f32x4){bb, bb, bb, bb};
            acc[1][n] = (f32x4){bb, bb, bb, bb};
        }
        C0_LOAD(0, pah, pal, pbh, pbl);
#pragma unroll 1
        for (int it = 0; it < 18; it += 2) {
            C0_LOAD(it + 1, qah, qal, qbh, qbl);
            FRAG_MFMA2(pah, pal, pbh, pbl);
            if (it + 2 < 18) C0_LOAD(it + 2, pah, pal, pbh, pbl);
            FRAG_MFMA2(qah, qal, qbh, qbl);
        }
        __syncthreads();   // all h0 reads complete before overwrite
        // store u = relu(v*m)*m into h1 rows l1<34; mgrp1 (base 18) keeps only l1>=32
#pragma unroll
        for (int f = 0; f < 2; ++f) {
            if (f < nf) {
                int fb = mgrp ? 18 : f * 16;
#pragma unroll
                for (int n = 0; n < 6; ++n) {
                    int col = (nhalf * 6 + n) * 16 + m;
#pragma unroll
                    for (int r = 0; r < 4; ++r) {
                        int l1 = fb + rbase + r;
                        bool keep = mgrp ? (l1 >= 32 && l1 < 34) : true;
                        if (keep) {
                            float mm = m_s[l1 + 1];
                            float u = fmaxf(acc[f][n][r] * mm, 0.f) * mm;
                            ushort_t hi, lo; split_bf(u, hi, lo);
                            hbuf[l1 * HPITCH + col] = hi;
                            hbuf[l1 * HPITCH + H + col] = lo;
                        }
                    }
                }
            }
        }
    }
    __syncthreads();

    // LN0 stats: 4 threads per row, vectorized short8 reads, shfl reduce
    {
        int row = tid >> 2;
        int q = tid & 3;
        if (row < 34) {
            float s = 0.f, ss = 0.f;
#pragma unroll
            for (int i = 0; i < 6; ++i) {
                int c0 = q * 48 + i * 8;
                short8 vh = *(const short8*)(hbuf + row * HPITCH + c0);
                short8 vl = *(const short8*)(hbuf + row * HPITCH + H + c0);
#pragma unroll
                for (int k2 = 0; k2 < 8; ++k2) {
                    float v = bf2f((ushort_t)vh[k2]) + bf2f((ushort_t)vl[k2]);
                    s += v; ss += v * v;
                }
            }
            s  += __shfl_xor(s, 1);  s  += __shfl_xor(s, 2);
            ss += __shfl_xor(ss, 1); ss += __shfl_xor(ss, 2);
            if (q == 0) {
                float mean = s * (1.f / (float)H);
                mstat[row] = mean;
                rstat[row] = rsqrtf(ss * (1.f / (float)H) - mean * mean + 1e-5f);
            }
        }
    }
    __syncthreads();
    // LN0 apply in place (vectorized), * mask^2
    for (int idx = tid; idx < 34 * 24; idx += 256) {
        int row = idx / 24;
        int c0 = (idx - row * 24) * 8;
        float mean = mstat[row], rstd = rstat[row];
        float mm = m_s[row + 1];
        float mm2 = mm * mm;
        short8 vh = *(const short8*)(hbuf + row * HPITCH + c0);
        short8 vl = *(const short8*)(hbuf + row * HPITCH + H + c0);
        ushort_t th[8], tl[8];
#pragma unroll
        for (int k2 = 0; k2 < 8; ++k2) {
            int c = c0 + k2;
            float v = bf2f((ushort_t)vh[k2]) + bf2f((ushort_t)vl[k2]);
            float y = ((v - mean) * rstd * g0_s[c] + b0_s[c]) * mm2;
            split_bf(y, th[k2], tl[k2]);
        }
        *(short8*)(hbuf + row * HPITCH + c0) = *(short8*)th;
        *(short8*)(hbuf + row * HPITCH + H + c0) = *(short8*)tl;
    }
    __syncthreads();

    // ================= stage C1: conv1 (taps=3), prefetched ======
    {
        f32x4 acc1[6];
#pragma unroll
        for (int n = 0; n < 6; ++n) {
            float bb = c1_b[(nhalf * 6 + n) * 16 + m];
            acc1[n] = (f32x4){bb, bb, bb, bb};
        }
        C1_LOAD(0, pah[0], pal[0], pbh, pbl);
#pragma unroll 1
        for (int it = 0; it < 18; it += 2) {
            C1_LOAD(it + 1, qah[0], qal[0], qbh, qbl);
            C1_MFMA(pah[0], pal[0], pbh, pbl);
            if (it + 2 < 18) C1_LOAD(it + 2, pah[0], pal[0], pbh, pbl);
            C1_MFMA(qah[0], qal[0], qbh, qbl);
        }
        __syncthreads();   // all h1 reads complete before overwrite
        // store w = relu(v*m)*m into rows 0..31
#pragma unroll
        for (int n = 0; n < 6; ++n) {
            int col = (nhalf * 6 + n) * 16 + m;
#pragma unroll
            for (int r = 0; r < 4; ++r) {
                int l2 = mgrp * 16 + rbase + r;              // < 32
                float mm = m_s[l2 + 2];
                float u = fmaxf(acc1[n][r] * mm, 0.f) * mm;
                ushort_t hi, lo; split_bf(u, hi, lo);
                hbuf[l2 * HPITCH + col] = hi;
                hbuf[l2 * HPITCH + H + col] = lo;
            }
        }
    }
    __syncthreads();

    // LN1 stats: 4 threads per row (rows 0..31)
    {
        int row = tid >> 2;
        int q = tid & 3;
        if (row < 32) {
            float s = 0.f, ss = 0.f;
#pragma unroll
            for (int i = 0; i < 6; ++i) {
                int c0 = q * 48 + i * 8;
                short8 vh = *(const short8*)(hbuf + row * HPITCH + c0);
                short8 vl = *(const short8*)(hbuf + row * HPITCH + H + c0);
#pragma unroll
                for (int k2 = 0; k2 < 8; ++k2) {
                    float v = bf2f((ushort_t)vh[k2]) + bf2f((ushort_t)vl[k2]);
                    s += v; ss += v * v;
                }
            }
            s  += __shfl_xor(s, 1);  s  += __shfl_xor(s, 2);
            ss += __shfl_xor(ss, 1); ss += __shfl_xor(ss, 2);
            if (q == 0) {
                float mean = s * (1.f / (float)H);
                mstat[row] = mean;
                rstat[row] = rsqrtf(ss * (1.f / (float)H) - mean * mean + 1e-5f);
            }
        }
    }
    __syncthreads();

    // fused final projection: 8 threads per row, 24 chans each, shfl reduce
    {
        int row = tid >> 3;          // 0..31
        int q = tid & 7;
        float mean = mstat[row], rstd = rstat[row], mk = m_s[row + 2];
        float a0 = 0.f, a1 = 0.f, a2 = 0.f, a3 = 0.f;
#pragma unroll
        for (int i = 0; i < 3; ++i) {
            int c0 = q * 24 + i * 8;
            short8 vh = *(const short8*)(hbuf + row * HPITCH + c0);
            short8 vl = *(const short8*)(hbuf + row * HPITCH + H + c0);
#pragma unroll
            for (int k2 = 0; k2 < 8; ++k2) {
                int c = c0 + k2;
                float v = bf2f((ushort_t)vh[k2]) + bf2f((ushort_t)vl[k2]);
                float y = ((v - mean) * rstd * g1_s[c] + b1_s[c]) * mk;
                a0 += lw_s[0 * H + c] * y;
                a1 += lw_s[1 * H + c] * y;
                a2 += lw_s[2 * H + c] * y;
                a3 += lw_s[3 * H + c] * y;
            }
        }
        a0 += __shfl_xor(a0, 1); a0 += __shfl_xor(a0, 2); a0 += __shfl_xor(a0, 4);
        a1 += __shfl_xor(a1, 1); a1 += __shfl_xor(a1, 2); a1 += __shfl_xor(a1, 4);
        a2 += __shfl_xor(a2, 1); a2 += __shfl_xor(a2, 2); a2 += __shfl_xor(a2, 4);
        a3 += __shfl_xor(a3, 1); a3 += __shfl_xor(a3, 2); a3 += __shfl_xor(a3, 4);
        if (q == 0) {
            int t = t0 + row;
            float* ob = out + (size_t)b * OUT * N_PH + t;
            ob[0 * N_PH] = (a0 + lb[0]) * mk;
            ob[1 * N_PH] = (a1 + lb[1]) * mk;
            ob[2 * N_PH] = (a2 + lb[2]) * mk;
            ob[3 * N_PH] = (a3 + lb[3]) * mk;
        }
    }
}

extern "C" void kernel_launch(void* const* d_in, const int* in_sizes, int n_in,
                              void* d_out, int out_size, void* d_ws, size_t ws_size,
                              hipStream_t stream) {
    const float* x      = (const float*)d_in[0];
    const float* x_mask = (const float*)d_in[1];
    const int*   w      = (const int*)d_in[2];
    const float* pre_w  = (const float*)d_in[3];
    const float* pre_b  = (const float*)d_in[4];
    const float* conv0_w = (const float*)d_in[5];
    const float* conv0_b = (const float*)d_in[6];
    const float* ln0_g   = (const float*)d_in[7];
    const float* ln0_b   = (const float*)d_in[8];
    const float* conv1_w = (const float*)d_in[9];
    const float* conv1_b = (const float*)d_in[10];
    const float* ln1_g   = (const float*)d_in[11];
    const float* ln1_b   = (const float*)d_in[12];
    const float* lin_w   = (const float*)d_in[13];
    const float* lin_b   = (const float*)d_in[14];
    float* out = (float*)d_out;

    // workspace layout
    char* ws = (char*)d_ws;
    size_t off = 0;
    ushort_t* specT = (ushort_t*)(ws + off); off += (size_t)B * N_PH * ROWP * sizeof(ushort_t);
    ushort_t* wpre  = (ushort_t*)(ws + off); off += (size_t)2 * 36864 * sizeof(ushort_t);
    ushort_t* w0t   = (ushort_t*)(ws + off); off += (size_t)2 * 110592 * sizeof(ushort_t);
    ushort_t* w1t   = (ushort_t*)(ws + off); off += (size_t)2 * 110592 * sizeof(ushort_t);
    int* ends       = (int*)(ws + off);      off += (size_t)B * N_PH * sizeof(int);

    // weight fragments + per-batch duration scans, one dispatch
    prep_kernel<<<NWF + B, 256, 0, stream>>>(pre_w, conv0_w, conv1_w, w,
                                             wpre, w0t, w1t, ends);

    // segment mean -> time-major split bf16
    segmean_direct_kernel<<<B * 32, 256, 0, stream>>>(x, ends, specT);

    // whole post-segmean chain, one dispatch, independent 32-row tiles
    chain_kernel<<<dim3(N_PH / TILE, B), 256, 0, stream>>>(
        specT, wpre, w0t, w1t, pre_b, conv0_b, conv1_b, x_mask,
        ln0_g, ln0_b, ln1_g, ln1_b, lin_w, lin_b, out);
}

// Round 14
// 365.922 us; speedup vs baseline: 1.0628x; 1.0628x over previous
//
#include <hip/hip_runtime.h>
#include <hip/hip_bf16.h>

#define B 32
#define C_IN 192
#define T 8192
#define H 192
#define N_PH 1024
#define OUT 4
#define ROWP (2 * H)          // specT row pitch: hi plane [0,H), lo plane [H,2H)
#define HPITCH 392            // hbuf row pitch (ushort): 784B, 16B-aligned
#define TILE 32               // output rows per chain block

typedef __attribute__((ext_vector_type(8))) short short8;
typedef __attribute__((ext_vector_type(4))) float f32x4;
typedef unsigned short ushort_t;

__device__ inline ushort_t f2bf(float f) {
    unsigned u = __builtin_bit_cast(unsigned, f);
    unsigned r = u + 0x7fffu + ((u >> 16) & 1u);   // RNE
    return (ushort_t)(r >> 16);
}
__device__ inline float bf2f(ushort_t h) {
    unsigned u = ((unsigned)h) << 16;
    return __builtin_bit_cast(float, u);
}
// split x into hi+lo bf16 pair (~17-bit effective mantissa) -- accuracy-mandatory
__device__ inline void split_bf(float x, ushort_t& hi, ushort_t& lo) {
    hi = f2bf(x);
    lo = f2bf(x - bf2f(hi));
}

// ---------------- weight prep: MFMA-fragment-ordered, split hi/lo -----------
__device__ inline void wfrag_one(const float* __restrict__ w, ushort_t* __restrict__ wtf,
                                 int taps, int idx, int ntot) {
    int j  = idx & 7;
    int l  = (idx >> 3) & 63;
    int slot = idx >> 9;             // (kt*6 + s)*12 + nt
    int nt = slot % 12;
    int ss = (slot / 12) % 6;
    int kt = slot / 72;
    int o  = nt * 16 + (l & 15);
    int i  = ss * 32 + ((l >> 4) << 3) + j;
    float v = (taps == 1) ? w[o * C_IN + i] : w[(o * H + i) * 3 + kt];
    ushort_t hi, lo;
    split_bf(v, hi, lo);
    wtf[idx] = hi;
    wtf[idx + ntot] = lo;
}

#define NWF 1008   // ceil((36864 + 2*110592)/256)
__global__ __launch_bounds__(256) void prep_kernel(
    const float* __restrict__ pw, const float* __restrict__ w0,
    const float* __restrict__ w1, const int* __restrict__ wdur,
    ushort_t* __restrict__ wpre, ushort_t* __restrict__ w0t,
    ushort_t* __restrict__ w1t, int* __restrict__ ends)
{
    int blk = blockIdx.x;
    int tid = threadIdx.x;
    const int n1 = 36864, n3 = 110592;
    if (blk < NWF) {
        int idx = blk * 256 + tid;
        if (idx < n1) { wfrag_one(pw, wpre, 1, idx, n1); return; }
        idx -= n1;
        if (idx < n3) { wfrag_one(w0, w0t, 3, idx, n3); return; }
        idx -= n3;
        if (idx < n3) wfrag_one(w1, w1t, 3, idx, n3);
        return;
    }
    int b = blk - NWF;
    __shared__ int part[256];
    int4 w4 = ((const int4*)(wdur + b * N_PH))[tid];
    int c0 = w4.x, c1 = c0 + w4.y, c2 = c1 + w4.z, c3 = c2 + w4.w;
    part[tid] = c3;
    __syncthreads();
    for (int off = 1; off < 256; off <<= 1) {
        int v = (tid >= off) ? part[tid - off] : 0;
        __syncthreads();
        part[tid] += v;
        __syncthreads();
    }
    int pre = tid ? part[tid - 1] : 0;
    int4 e4;
    e4.x = pre + c0; e4.y = pre + c1; e4.z = pre + c2; e4.w = pre + c3;
    ((int4*)(ends + b * N_PH))[tid] = e4;
}

// ---------------- segment mean, direct to time-major split-bf16 specT ----------------
__global__ __launch_bounds__(256) void segmean_direct_kernel(
    const float* __restrict__ x, const int* __restrict__ ends,
    ushort_t* __restrict__ specT)
{
    int b  = blockIdx.x >> 5;
    int jt = (blockIdx.x & 31) * 32;
    int tid = threadIdx.x;
    int j_loc = tid & 31;
    int cg0 = tid >> 5;            // 0..7
    int j = jt + j_loc;

    __shared__ float sm[32][193];

    const int* eb = ends + b * N_PH;
    int e0 = eb[j];
    int s0 = j ? eb[j - 1] : 0;
    int len = e0 - s0;
    float inv = (len > 0) ? 1.f / (float)len : 0.f;

    const float* xb = x + (size_t)b * C_IN * T;
#pragma unroll 1
    for (int c = cg0; c < C_IN; c += 8) {
        const float* xr = xb + (size_t)c * T;
        float sum = 0.f;
        for (int t = s0; t < e0; ++t) sum += xr[t];
        sm[j_loc][c] = sum * inv;
    }
    __syncthreads();

    int r = tid >> 3;
    int g = tid & 7;
    ushort_t* ob = specT + ((size_t)b * N_PH + jt + r) * ROWP;
#pragma unroll
    for (int i0 = 0; i0 < 24; i0 += 8) {
        ushort_t th[8], tl[8];
#pragma unroll
        for (int k2 = 0; k2 < 8; ++k2) {
            int c = g * 24 + i0 + k2;
            split_bf(sm[r][c], th[k2], tl[k2]);
        }
        *(short8*)(ob + g * 24 + i0) = *(short8*)th;
        *(short8*)(ob + H + g * 24 + i0) = *(short8*)tl;
    }
}

// ---------------- fused chain, TILE=32, wave-owns-all-M (weight dedup) ----
// R13 falsified per-wave ILP as the lever; R12 falsified occupancy. New theory:
// redundant weight reads through L2 (each nhalf slice read by 2 waves; ~2 MB/block,
// ~2.1 GB total >= 61us at L2 ceiling) + M-frag imbalance (mgrp0 12 frag-slots vs
// mgrp1 6 per iter). This version: wave wv owns n-slots {3wv..3wv+2} x ALL M-frags.
// Weight slices read ONCE per block (-50% L2), all waves identical work, VGPR ~110
// so launch_bounds(256,4) keeps R12's 4 blocks/CU. Per-output arithmetic order
// unchanged -> absmax must stay 0.00390625.
__global__ __launch_bounds__(256, 4) void chain_kernel(
    const ushort_t* __restrict__ specT,
    const ushort_t* __restrict__ wpre, const ushort_t* __restrict__ w0t,
    const ushort_t* __restrict__ w1t,
    const float* __restrict__ pre_b, const float* __restrict__ c0_b,
    const float* __restrict__ c1_b,
    const float* __restrict__ mask,
    const float* __restrict__ g0, const float* __restrict__ be0,
    const float* __restrict__ g1, const float* __restrict__ be1,
    const float* __restrict__ lw, const float* __restrict__ lb,
    float* __restrict__ out)
{
    const int b  = blockIdx.y;
    const int t0 = blockIdx.x * TILE;
    const int tid = threadIdx.x;
    const int lane = tid & 63;
    const int wv = tid >> 6;            // wave owns n-slots 3*wv .. 3*wv+2
    const int m = lane & 15;
    const int kg = (lane >> 4) << 3;
    const int rbase = (lane >> 4) << 2;
    const int ns0 = wv * 3;             // first owned n-slot

    __shared__ ushort_t hbuf[36 * HPITCH];          // 28.2 KB
    __shared__ float g0_s[H], b0_s[H], g1_s[H], b1_s[H];
    __shared__ float lw_s[OUT * H];
    __shared__ float m_s[36], mstat[34], rstat[34];

    if (tid < H) { g0_s[tid] = g0[tid]; b0_s[tid] = be0[tid];
                   g1_s[tid] = g1[tid]; b1_s[tid] = be1[tid]; }
    if (tid < 36) {
        int grow = t0 - 2 + tid;
        m_s[tid] = (grow >= 0 && grow < N_PH) ? mask[b * N_PH + grow] : 0.f;
    }
    for (int i = tid; i < OUT * H; i += 256) lw_s[i] = lw[i];
    __syncthreads();

    const short8 z8 = {0, 0, 0, 0, 0, 0, 0, 0};

    // ================= stage P: pre-linear (taps=1, K=192) =================
    // frag bases {0,16,32} (rows t0-2 .. t0+45, keep l<36); 3 n-slots per wave
    {
        f32x4 acc[3][3];
#pragma unroll
        for (int j = 0; j < 3; ++j) {
            float bb = pre_b[(ns0 + j) * 16 + m];
#pragma unroll
            for (int f = 0; f < 3; ++f) acc[f][j] = (f32x4){bb, bb, bb, bb};
        }
        const ushort_t* inb = specT + (size_t)b * N_PH * ROWP;
#pragma unroll 1
        for (int s = 0; s < 6; ++s) {
            short8 ah[3], al[3], bh[3], bl[3];
#pragma unroll
            for (int f = 0; f < 3; ++f) {
                int trow = t0 - 2 + f * 16 + m;
                if ((unsigned)trow < (unsigned)N_PH) {
                    const ushort_t* ar = inb + (size_t)trow * ROWP + s * 32 + kg;
                    ah[f] = *(const short8*)ar;
                    al[f] = *(const short8*)(ar + H);
                } else { ah[f] = z8; al[f] = z8; }
            }
            const ushort_t* wb = wpre + ((size_t)(s * 12 + ns0) << 9) + (lane << 3);
#pragma unroll
            for (int j = 0; j < 3; ++j) {
                bh[j] = *(const short8*)(wb + (j << 9));
                bl[j] = *(const short8*)(wb + (j << 9) + 36864);
            }
#pragma unroll
            for (int f = 0; f < 3; ++f)
#pragma unroll
                for (int j = 0; j < 3; ++j) {
                    acc[f][j] = __builtin_amdgcn_mfma_f32_16x16x32_bf16(ah[f], bh[j], acc[f][j], 0, 0, 0);
                    acc[f][j] = __builtin_amdgcn_mfma_f32_16x16x32_bf16(al[f], bh[j], acc[f][j], 0, 0, 0);
                    acc[f][j] = __builtin_amdgcn_mfma_f32_16x16x32_bf16(ah[f], bl[j], acc[f][j], 0, 0, 0);
                }
        }
        // store h0 = pre_out * mask, rows l < 36
#pragma unroll
        for (int f = 0; f < 3; ++f) {
#pragma unroll
            for (int j = 0; j < 3; ++j) {
                int col = (ns0 + j) * 16 + m;
#pragma unroll
                for (int r = 0; r < 4; ++r) {
                    int l = f * 16 + rbase + r;
                    if (l < 36) {
                        float v = acc[f][j][r] * m_s[l];
                        ushort_t hi, lo; split_bf(v, hi, lo);
                        hbuf[l * HPITCH + col] = hi;
                        hbuf[l * HPITCH + H + col] = lo;
                    }
                }
            }
        }
    }
    __syncthreads();

    // ================= stage C0: conv0 (taps=3) =================
    // frag bases {0,16,18}: f0,f1 keep all (l1 0..31); f2 (rows 18..33, reads <=35)
    // keeps only l1 >= 32. 3 n-slots per wave.
    {
        f32x4 acc[3][3];
#pragma unroll
        for (int j = 0; j < 3; ++j) {
            float bb = c0_b[(ns0 + j) * 16 + m];
#pragma unroll
            for (int f = 0; f < 3; ++f) acc[f][j] = (f32x4){bb, bb, bb, bb};
        }
#pragma unroll 1
        for (int kt = 0; kt < 3; ++kt)
#pragma unroll 1
            for (int s = 0; s < 6; ++s) {
                short8 ah[3], al[3], bh[3], bl[3];
#pragma unroll
                for (int f = 0; f < 3; ++f) {
                    int fb = (f == 2) ? 18 : f * 16;
                    const ushort_t* ar = hbuf + (fb + m + kt) * HPITCH + s * 32 + kg;
                    ah[f] = *(const short8*)ar;
                    al[f] = *(const short8*)(ar + H);
                }
                const ushort_t* wb = w0t + ((size_t)((kt * 6 + s) * 12 + ns0) << 9) + (lane << 3);
#pragma unroll
                for (int j = 0; j < 3; ++j) {
                    bh[j] = *(const short8*)(wb + (j << 9));
                    bl[j] = *(const short8*)(wb + (j << 9) + 110592);
                }
#pragma unroll
                for (int f = 0; f < 3; ++f)
#pragma unroll
                    for (int j = 0; j < 3; ++j) {
                        acc[f][j] = __builtin_amdgcn_mfma_f32_16x16x32_bf16(ah[f], bh[j], acc[f][j], 0, 0, 0);
                        acc[f][j] = __builtin_amdgcn_mfma_f32_16x16x32_bf16(al[f], bh[j], acc[f][j], 0, 0, 0);
                        acc[f][j] = __builtin_amdgcn_mfma_f32_16x16x32_bf16(ah[f], bl[j], acc[f][j], 0, 0, 0);
                    }
            }
        __syncthreads();   // all h0 reads complete before overwrite
        // store u = relu(v*m)*m into h1 rows: f0/f1 all, f2 only l1>=32
#pragma unroll
        for (int f = 0; f < 3; ++f) {
            int fb = (f == 2) ? 18 : f * 16;
#pragma unroll
            for (int j = 0; j < 3; ++j) {
                int col = (ns0 + j) * 16 + m;
#pragma unroll
                for (int r = 0; r < 4; ++r) {
                    int l1 = fb + rbase + r;
                    bool keep = (f == 2) ? (l1 >= 32 && l1 < 34) : true;
                    if (keep) {
                        float mm = m_s[l1 + 1];
                        float u = fmaxf(acc[f][j][r] * mm, 0.f) * mm;
                        ushort_t hi, lo; split_bf(u, hi, lo);
                        hbuf[l1 * HPITCH + col] = hi;
                        hbuf[l1 * HPITCH + H + col] = lo;
                    }
                }
            }
        }
    }
    __syncthreads();

    // LN0 stats: 4 threads per row, vectorized short8 reads, shfl reduce
    {
        int row = tid >> 2;
        int q = tid & 3;
        if (row < 34) {
            float s = 0.f, ss = 0.f;
#pragma unroll
            for (int i = 0; i < 6; ++i) {
                int c0 = q * 48 + i * 8;
                short8 vh = *(const short8*)(hbuf + row * HPITCH + c0);
                short8 vl = *(const short8*)(hbuf + row * HPITCH + H + c0);
#pragma unroll
                for (int k2 = 0; k2 < 8; ++k2) {
                    float v = bf2f((ushort_t)vh[k2]) + bf2f((ushort_t)vl[k2]);
                    s += v; ss += v * v;
                }
            }
            s  += __shfl_xor(s, 1);  s  += __shfl_xor(s, 2);
            ss += __shfl_xor(ss, 1); ss += __shfl_xor(ss, 2);
            if (q == 0) {
                float mean = s * (1.f / (float)H);
                mstat[row] = mean;
                rstat[row] = rsqrtf(ss * (1.f / (float)H) - mean * mean + 1e-5f);
            }
        }
    }
    __syncthreads();
    // LN0 apply in place (vectorized), * mask^2
    for (int idx = tid; idx < 34 * 24; idx += 256) {
        int row = idx / 24;
        int c0 = (idx - row * 24) * 8;
        float mean = mstat[row], rstd = rstat[row];
        float mm = m_s[row + 1];
        float mm2 = mm * mm;
        short8 vh = *(const short8*)(hbuf + row * HPITCH + c0);
        short8 vl = *(const short8*)(hbuf + row * HPITCH + H + c0);
        ushort_t th[8], tl[8];
#pragma unroll
        for (int k2 = 0; k2 < 8; ++k2) {
            int c = c0 + k2;
            float v = bf2f((ushort_t)vh[k2]) + bf2f((ushort_t)vl[k2]);
            float y = ((v - mean) * rstd * g0_s[c] + b0_s[c]) * mm2;
            split_bf(y, th[k2], tl[k2]);
        }
        *(short8*)(hbuf + row * HPITCH + c0) = *(short8*)th;
        *(short8*)(hbuf + row * HPITCH + H + c0) = *(short8*)tl;
    }
    __syncthreads();

    // ================= stage C1: conv1 (taps=3) =================
    // frag bases {0,16} (reads h1 rows <= 33); 3 n-slots per wave.
    {
        f32x4 acc[2][3];
#pragma unroll
        for (int j = 0; j < 3; ++j) {
            float bb = c1_b[(ns0 + j) * 16 + m];
            acc[0][j] = (f32x4){bb, bb, bb, bb};
            acc[1][j] = (f32x4){bb, bb, bb, bb};
        }
#pragma unroll 1
        for (int kt = 0; kt < 3; ++kt)
#pragma unroll 1
            for (int s = 0; s < 6; ++s) {
                short8 ah[2], al[2], bh[3], bl[3];
#pragma unroll
                for (int f = 0; f < 2; ++f) {
                    const ushort_t* ar = hbuf + (f * 16 + m + kt) * HPITCH + s * 32 + kg;
                    ah[f] = *(const short8*)ar;
                    al[f] = *(const short8*)(ar + H);
                }
                const ushort_t* wb = w1t + ((size_t)((kt * 6 + s) * 12 + ns0) << 9) + (lane << 3);
#pragma unroll
                for (int j = 0; j < 3; ++j) {
                    bh[j] = *(const short8*)(wb + (j << 9));
                    bl[j] = *(const short8*)(wb + (j << 9) + 110592);
                }
#pragma unroll
                for (int f = 0; f < 2; ++f)
#pragma unroll
                    for (int j = 0; j < 3; ++j) {
                        acc[f][j] = __builtin_amdgcn_mfma_f32_16x16x32_bf16(ah[f], bh[j], acc[f][j], 0, 0, 0);
                        acc[f][j] = __builtin_amdgcn_mfma_f32_16x16x32_bf16(al[f], bh[j], acc[f][j], 0, 0, 0);
                        acc[f][j] = __builtin_amdgcn_mfma_f32_16x16x32_bf16(ah[f], bl[j], acc[f][j], 0, 0, 0);
                    }
            }
        __syncthreads();   // all h1 reads complete before overwrite
        // store w = relu(v*m)*m into rows 0..31
#pragma unroll
        for (int f = 0; f < 2; ++f) {
#pragma unroll
            for (int j = 0; j < 3; ++j) {
                int col = (ns0 + j) * 16 + m;
#pragma unroll
                for (int r = 0; r < 4; ++r) {
                    int l2 = f * 16 + rbase + r;             // < 32
                    float mm = m_s[l2 + 2];
                    float u = fmaxf(acc[f][j][r] * mm, 0.f) * mm;
                    ushort_t hi, lo; split_bf(u, hi, lo);
                    hbuf[l2 * HPITCH + col] = hi;
                    hbuf[l2 * HPITCH + H + col] = lo;
                }
            }
        }
    }
    __syncthreads();

    // LN1 stats: 4 threads per row (rows 0..31)
    {
        int row = tid >> 2;
        int q = tid & 3;
        if (row < 32) {
            float s = 0.f, ss = 0.f;
#pragma unroll
            for (int i = 0; i < 6; ++i) {
                int c0 = q * 48 + i * 8;
                short8 vh = *(const short8*)(hbuf + row * HPITCH + c0);
                short8 vl = *(const short8*)(hbuf + row * HPITCH + H + c0);
#pragma unroll
                for (int k2 = 0; k2 < 8; ++k2) {
                    float v = bf2f((ushort_t)vh[k2]) + bf2f((ushort_t)vl[k2]);
                    s += v; ss += v * v;
                }
            }
            s  += __shfl_xor(s, 1);  s  += __shfl_xor(s, 2);
            ss += __shfl_xor(ss, 1); ss += __shfl_xor(ss, 2);
            if (q == 0) {
                float mean = s * (1.f / (float)H);
                mstat[row] = mean;
                rstat[row] = rsqrtf(ss * (1.f / (float)H) - mean * mean + 1e-5f);
            }
        }
    }
    __syncthreads();

    // fused final projection: 8 threads per row, 24 chans each, shfl reduce
    {
        int row = tid >> 3;          // 0..31
        int q = tid & 7;
        float mean = mstat[row], rstd = rstat[row], mk = m_s[row + 2];
        float a0 = 0.f, a1 = 0.f, a2 = 0.f, a3 = 0.f;
#pragma unroll
        for (int i = 0; i < 3; ++i) {
            int c0 = q * 24 + i * 8;
            short8 vh = *(const short8*)(hbuf + row * HPITCH + c0);
            short8 vl = *(const short8*)(hbuf + row * HPITCH + H + c0);
#pragma unroll
            for (int k2 = 0; k2 < 8; ++k2) {
                int c = c0 + k2;
                float v = bf2f((ushort_t)vh[k2]) + bf2f((ushort_t)vl[k2]);
                float y = ((v - mean) * rstd * g1_s[c] + b1_s[c]) * mk;
                a0 += lw_s[0 * H + c] * y;
                a1 += lw_s[1 * H + c] * y;
                a2 += lw_s[2 * H + c] * y;
                a3 += lw_s[3 * H + c] * y;
            }
        }
        a0 += __shfl_xor(a0, 1); a0 += __shfl_xor(a0, 2); a0 += __shfl_xor(a0, 4);
        a1 += __shfl_xor(a1, 1); a1 += __shfl_xor(a1, 2); a1 += __shfl_xor(a1, 4);
        a2 += __shfl_xor(a2, 1); a2 += __shfl_xor(a2, 2); a2 += __shfl_xor(a2, 4);
        a3 += __shfl_xor(a3, 1); a3 += __shfl_xor(a3, 2); a3 += __shfl_xor(a3, 4);
        if (q == 0) {
            int t = t0 + row;
            float* ob = out + (size_t)b * OUT * N_PH + t;
            ob[0 * N_PH] = (a0 + lb[0]) * mk;
            ob[1 * N_PH] = (a1 + lb[1]) * mk;
            ob[2 * N_PH] = (a2 + lb[2]) * mk;
            ob[3 * N_PH] = (a3 + lb[3]) * mk;
        }
    }
}

extern "C" void kernel_launch(void* const* d_in, const int* in_sizes, int n_in,
                              void* d_out, int out_size, void* d_ws, size_t ws_size,
                              hipStream_t stream) {
    const float* x      = (const float*)d_in[0];
    const float* x_mask = (const float*)d_in[1];
    const int*   w      = (const int*)d_in[2];
    const float* pre_w  = (const float*)d_in[3];
    const float* pre_b  = (const float*)d_in[4];
    const float* conv0_w = (const float*)d_in[5];
    const float* conv0_b = (const float*)d_in[6];
    const float* ln0_g   = (const float*)d_in[7];
    const float* ln0_b   = (const float*)d_in[8];
    const float* conv1_w = (const float*)d_in[9];
    const float* conv1_b = (const float*)d_in[10];
    const float* ln1_g   = (const float*)d_in[11];
    const float* ln1_b   = (const float*)d_in[12];
    const float* lin_w   = (const float*)d_in[13];
    const float* lin_b   = (const float*)d_in[14];
    float* out = (float*)d_out;

    // workspace layout
    char* ws = (char*)d_ws;
    size_t off = 0;
    ushort_t* specT = (ushort_t*)(ws + off); off += (size_t)B * N_PH * ROWP * sizeof(ushort_t);
    ushort_t* wpre  = (ushort_t*)(ws + off); off += (size_t)2 * 36864 * sizeof(ushort_t);
    ushort_t* w0t   = (ushort_t*)(ws + off); off += (size_t)2 * 110592 * sizeof(ushort_t);
    ushort_t* w1t   = (ushort_t*)(ws + off); off += (size_t)2 * 110592 * sizeof(ushort_t);
    int* ends       = (int*)(ws + off);      off += (size_t)B * N_PH * sizeof(int);

    // weight fragments + per-batch duration scans, one dispatch
    prep_kernel<<<NWF + B, 256, 0, stream>>>(pre_w, conv0_w, conv1_w, w,
                                             wpre, w0t, w1t, ends);

    // segment mean -> time-major split bf16
    segmean_direct_kernel<<<B * 32, 256, 0, stream>>>(x, ends, specT);

    // whole post-segmean chain, one dispatch, independent 32-row tiles
    chain_kernel<<<dim3(N_PH / TILE, B), 256, 0, stream>>>(
        specT, wpre, w0t, w1t, pre_b, conv0_b, conv1_b, x_mask,
        ln0_g, ln0_b, ln1_g, ln1_b, lin_w, lin_b, out);
}